// Round 7
// baseline (189.849 us; speedup 1.0000x reference)
//
#include <hip/hip_runtime.h>
#include <hip/hip_bf16.h>

// PraxisMemory: one-shot delta-rule memory. B=4,H=16,S=4096,D=64, all f32 I/O.
//
// Gram reformulation:  M = W0 + sigma_k^T @ VU
//                        = W0 + sigma_k^T @ V - (sigma_k^T diag(1/den) sigma_k) @ W0
//                        = W0 + MP1 - G @ W0
// k1 v7: 256-thr blocks, wave w = (chunk-half w>>1, d-half w&1). Each 32-row
//   chunk is processed by 2 waves covering complementary 32-d strips (2x
//   gather/VALU redundancy instead of R6's 4x). acc = 72 VGPR -> (256,3).
//   Cross-half reduce via LDS overlay + 2 barriers. Cheap round-half-up bf16.
// k_reduce: M = W0 + sum_p Mpart(bf16) -> MfinT bf16; z = z0 + sum Zpart.
// k2: 256-thr, grid BH*32, one 32-row group per wave, launch_bounds(256,8)
//   -> 32 waves/CU (VGPR 64).

#define B_  4
#define H_  16
#define S_  4096
#define D_  64
#define BH_ 64
#define EPS_ 1e-8f

typedef __attribute__((ext_vector_type(8))) short bf16x8;
typedef __attribute__((ext_vector_type(4))) float f32x4;
typedef __attribute__((ext_vector_type(4))) unsigned short u16x4;

__device__ __forceinline__ unsigned short f2bf(float x) {
    union { float f; unsigned u; } v; v.f = x;
    return (unsigned short)((v.u + 0x8000u) >> 16);   // round-half-up (cheap)
}
__device__ __forceinline__ float bf2f(unsigned short u) {
    union { unsigned u; float f; } v; v.u = ((unsigned)u) << 16;
    return v.f;
}
__device__ __forceinline__ float elup1(float x) {
    return x > 0.0f ? x + 1.0f : __expf(x);  // elu(x)+1
}
__device__ __forceinline__ f32x4 fzero() { f32x4 z = {0.f, 0.f, 0.f, 0.f}; return z; }

// ---------------------------------------------------------------------------
// Kernel 1. MFMA 16x16x32 bf16 conventions (verified across rounds):
//   A-frag: lane m = l&15, per-lane k = (l>>4)*8 + j
//   B-frag: lane n = l&15, same k bijection
//   C/D:    lane l, reg r -> row m = (l>>4)*4 + r, col n = l&15
// Wave (sh = w&1) owns d rows [sh*32, sh*32+32) (tiles sh*2, sh*2+1) for
// chunk-half (ch = w>>1). Column rotation col[q] = ((sh*2+q)&3)*16 + c16 makes
// the own-strip fragments compile-time (q=0,1).
// ---------------------------------------------------------------------------
__global__ __launch_bounds__(256, 3) void k1_states(
    const float* __restrict__ Kp, const float* __restrict__ Vp,
    const float* __restrict__ W0, const float* __restrict__ Z0,
    unsigned short* __restrict__ Mpart, float* __restrict__ Zpart, int NS)
{
    const int bid = blockIdx.x;
    const int bh  = bid / NS;
    const int p   = bid % NS;
    const int h   = bh & (H_ - 1);
    const int tid  = threadIdx.x;
    const int lane = tid & 63;
    const int w    = tid >> 6;
    const int c16  = lane & 15;
    const int g4   = lane >> 4;
    const int sh   = w & 1;       // d-half
    const int ch   = w >> 1;      // chunk-half

    __shared__ __align__(16) union {
        float G[4][16][68];       // per-wave G-strip round-trip (17 KiB)
        float R[4][32][68];       // per-wave result slabs for cross-half sum (35 KiB)
    } U;
    __shared__ float Zl[4][32];

    int   col[4];
    float z0l[4];
    #pragma unroll
    for (int q = 0; q < 4; ++q) {
        col[q] = (((sh * 2 + q) & 3) << 4) + c16;
        z0l[q] = Z0[h * 64 + col[q]];
    }

    bf16x8 ones;
    #pragma unroll
    for (int j = 0; j < 8; ++j) ones[j] = (short)0x3F80;  // bf16 1.0

    const size_t base   = (size_t)bh * S_ * D_;
    const int    schunk = S_ / NS;
    const int    nch    = schunk >> 5;      // 32-row chunks (even)
    const int    cbeg   = ch * (nch >> 1);
    const int    cend   = cbeg + (nch >> 1);

    f32x4 mp1[2][4], gac[2][4], zz[2];
    #pragma unroll
    for (int mt = 0; mt < 2; ++mt) {
        zz[mt] = fzero();
        #pragma unroll
        for (int i = 0; i < 4; ++i) { mp1[mt][i] = fzero(); gac[mt][i] = fzero(); }
    }

    #pragma unroll 1
    for (int c = cbeg; c < cend; ++c) {
        const float* kr = Kp + base + (size_t)(p * schunk + c * 32) * D_;
        const float* vr = Vp + base + (size_t)(p * schunk + c * 32) * D_;

        // ---- gather K^T (all 64 cols; needed for den + G's B) ----
        float kf[4][8];
        #pragma unroll
        for (int q = 0; q < 4; ++q)
        #pragma unroll
        for (int j = 0; j < 8; ++j)
            kf[q][j] = kr[(g4 * 8 + j) * 64 + col[q]];

        // ---- gather V^T (all 64 cols; MP1's B) ----
        float vf[4][8];
        #pragma unroll
        for (int nt = 0; nt < 4; ++nt)
        #pragma unroll
        for (int j = 0; j < 8; ++j)
            vf[nt][j] = vr[(g4 * 8 + j) * 64 + nt * 16 + c16];

        // ---- sigma + den ----
        float den[8];
        #pragma unroll
        for (int j = 0; j < 8; ++j) den[j] = 0.f;
        #pragma unroll
        for (int q = 0; q < 4; ++q)
        #pragma unroll
        for (int j = 0; j < 8; ++j) {
            float s = elup1(kf[q][j]);
            kf[q][j] = s;
            den[j] += s * z0l[q];
        }
        #pragma unroll
        for (int j = 0; j < 8; ++j) {
            float d = den[j];
            d += __shfl_xor(d, 1); d += __shfl_xor(d, 2);
            d += __shfl_xor(d, 4); d += __shfl_xor(d, 8);
            den[j] = __builtin_amdgcn_rcpf(d + EPS_);   // rd
        }

        // ---- fragments ----
        bf16x8 aown[2], skbS[4], vbf[4];
        #pragma unroll
        for (int mt = 0; mt < 2; ++mt)
        #pragma unroll
        for (int j = 0; j < 8; ++j) aown[mt][j] = (short)f2bf(kf[mt][j]);
        #pragma unroll
        for (int q = 0; q < 4; ++q)
        #pragma unroll
        for (int j = 0; j < 8; ++j) skbS[q][j] = (short)f2bf(kf[q][j] * den[j]);
        #pragma unroll
        for (int nt = 0; nt < 4; ++nt)
        #pragma unroll
        for (int j = 0; j < 8; ++j) vbf[nt][j] = (short)f2bf(vf[nt][j]);

        // ---- 18 MFMAs ----
        #pragma unroll
        for (int mt = 0; mt < 2; ++mt) {
            zz[mt] = __builtin_amdgcn_mfma_f32_16x16x32_bf16(aown[mt], ones, zz[mt], 0, 0, 0);
            #pragma unroll
            for (int nt = 0; nt < 4; ++nt)
                mp1[mt][nt] = __builtin_amdgcn_mfma_f32_16x16x32_bf16(aown[mt], vbf[nt], mp1[mt][nt], 0, 0, 0);
            #pragma unroll
            for (int q = 0; q < 4; ++q)
                gac[mt][q] = __builtin_amdgcn_mfma_f32_16x16x32_bf16(aown[mt], skbS[q], gac[mt][q], 0, 0, 0);
        }
    }

    // ================= epilogue =================
    // W0 B-frags (absolute cols), loaded once (L2-resident)
    bf16x8 wb[4][2];
    #pragma unroll
    for (int nt = 0; nt < 4; ++nt)
    #pragma unroll
    for (int kk = 0; kk < 2; ++kk)
    #pragma unroll
    for (int j = 0; j < 8; ++j)
        wb[nt][kk][j] = (short)f2bf(W0[(size_t)h * 4096 + (kk * 32 + g4 * 8 + j) * 64 + nt * 16 + c16]);

    // per-strip: G -> LDS -> A-frag -> GW0; rr = MP1 - GW0  (wave-private)
    f32x4 rr[2][4];
    #pragma unroll
    for (int mt = 0; mt < 2; ++mt) {
        #pragma unroll
        for (int q = 0; q < 4; ++q)
        #pragma unroll
        for (int r = 0; r < 4; ++r)
            U.G[w][g4 * 4 + r][(((sh * 2 + q) & 3) << 4) + c16] = gac[mt][q][r];

        bf16x8 ag[2];
        #pragma unroll
        for (int kk = 0; kk < 2; ++kk)
        #pragma unroll
        for (int j = 0; j < 8; ++j)
            ag[kk][j] = (short)f2bf(U.G[w][c16][kk * 32 + g4 * 8 + j]);

        #pragma unroll
        for (int nt = 0; nt < 4; ++nt) {
            f32x4 t = __builtin_amdgcn_mfma_f32_16x16x32_bf16(ag[0], wb[nt][0], fzero(), 0, 0, 0);
            t = __builtin_amdgcn_mfma_f32_16x16x32_bf16(ag[1], wb[nt][1], t, 0, 0, 0);
            rr[mt][nt] = mp1[mt][nt] - t;
        }
    }

    // z partials
    if (c16 == 0) {
        #pragma unroll
        for (int mt = 0; mt < 2; ++mt)
        #pragma unroll
        for (int r = 0; r < 4; ++r)
            Zl[w][mt * 16 + g4 * 4 + r] = zz[mt][r];
    }

    __syncthreads();   // all waves done with U.G before overlaying U.R

    #pragma unroll
    for (int mt = 0; mt < 2; ++mt)
    #pragma unroll
    for (int nt = 0; nt < 4; ++nt)
    #pragma unroll
    for (int r = 0; r < 4; ++r)
        U.R[w][mt * 16 + g4 * 4 + r][nt * 16 + c16] = rr[mt][nt][r];

    __syncthreads();

    // combine halves (waves sh and sh+2 cover the same d rows) + bf16 store
    unsigned short* mout = Mpart + ((size_t)p * BH_ + bh) * 4096;
    #pragma unroll
    for (int i = 0; i < 4; ++i) {
        int o = i * 1024 + tid * 4;        // linear d*64 + e
        int d = o >> 6, e = o & 63;
        int hf = d >> 5, dr = d & 31;
        u16x4 pk;
        #pragma unroll
        for (int j = 0; j < 4; ++j)
            pk[j] = f2bf(U.R[hf][dr][e + j] + U.R[hf + 2][dr][e + j]);
        *(u16x4*)(mout + o) = pk;
    }
    if (tid < 64) {
        Zpart[((size_t)p * BH_ + bh) * 64 + tid] =
            Zl[tid >> 5][tid & 31] + Zl[2 + (tid >> 5)][tid & 31];
    }
}

// ---------------------------------------------------------------------------
// Reduce: M = W0 + sum_p Mpart(bf16) -> MfinT bf16 [bh][e*64+d];
// z = z0 + sum Zpart. Grid = BH_*4; block handles d-rows [q*16, q*16+16).
// ---------------------------------------------------------------------------
__global__ void k_reduce(const unsigned short* __restrict__ Mpart, const float* __restrict__ Zpart,
                         const float* __restrict__ W0, const float* __restrict__ Z0,
                         unsigned short* __restrict__ MfinT, float* __restrict__ Zfin, int NS)
{
    const int bh = blockIdx.x >> 2, q = blockIdx.x & 3;
    const int h = bh & (H_ - 1), t = threadIdx.x;
    __shared__ float Ml[16][65];

    const int o = q * 1024 + t * 4;          // linear d*64+e
    f32x4 s = *(const f32x4*)(W0 + (size_t)h * 4096 + o);
    for (int p = 0; p < NS; ++p) {
        u16x4 v = *(const u16x4*)(Mpart + ((size_t)p * BH_ + bh) * 4096 + o);
        #pragma unroll
        for (int j = 0; j < 4; ++j) s[j] += bf2f(v[j]);
    }
    const int dl = t >> 4, e0 = (t & 15) * 4;
    #pragma unroll
    for (int j = 0; j < 4; ++j) Ml[dl][e0 + j] = s[j];
    __syncthreads();

    const int e = t >> 2, dd0 = (t & 3) * 4;
    u16x4 wv;
    #pragma unroll
    for (int j = 0; j < 4; ++j) wv[j] = f2bf(Ml[dd0 + j][e]);
    *(u16x4*)(MfinT + (size_t)bh * 4096 + e * 64 + q * 16 + dd0) = wv;

    if (q == 0 && t < 64) {
        float zs = Z0[h * 64 + t];
        for (int p = 0; p < NS; ++p) zs += Zpart[((size_t)p * BH_ + bh) * 64 + t];
        Zfin[bh * 64 + t] = zs;
    }
}

// ---------------------------------------------------------------------------
// Kernel 2: 256-thr, grid BH_*NS2; wave handles one 32-row group.
// launch_bounds(256,8): VGPR<=64 -> 8 blocks/CU = 32 waves/CU.
// RET^T = M^T @ SQ^T ; out = O + gate*(RET/norm - O). No LDS.
// ---------------------------------------------------------------------------
__global__ __launch_bounds__(256, 8) void k2_out(
    const float* __restrict__ Qp, const float* __restrict__ Op,
    const float* __restrict__ Bp, const unsigned short* __restrict__ MfinT,
    const float* __restrict__ Zfin, float* __restrict__ Out, int NS2)
{
    const int bh = blockIdx.x / NS2;
    const int p  = blockIdx.x % NS2;
    const int h  = bh & (H_ - 1);
    const int tid = threadIdx.x, lane = tid & 63, wave = tid >> 6;
    const int c16 = lane & 15, g4 = lane >> 4;

    float mzv[2][8];
    #pragma unroll
    for (int kk = 0; kk < 2; ++kk) {
        f32x4 a = *(const f32x4*)(Zfin + bh * 64 + kk * 32 + g4 * 8);
        f32x4 b = *(const f32x4*)(Zfin + bh * 64 + kk * 32 + g4 * 8 + 4);
        #pragma unroll
        for (int j = 0; j < 4; ++j) { mzv[kk][j] = a[j]; mzv[kk][4 + j] = b[j]; }
    }

    bf16x8 mf[4][2];  // M^T A-frags, straight b128 loads
    #pragma unroll
    for (int et = 0; et < 4; ++et)
    #pragma unroll
    for (int kk = 0; kk < 2; ++kk)
        mf[et][kk] = *(const bf16x8*)(MfinT + (size_t)bh * 4096 + (et * 16 + c16) * 64 + kk * 32 + g4 * 8);

    float gate[4][4];
    #pragma unroll
    for (int et = 0; et < 4; ++et)
    #pragma unroll
    for (int r = 0; r < 4; ++r) {
        float b = Bp[h * 64 + et * 16 + g4 * 4 + r];
        gate[et][r] = 1.0f / (1.0f + __expf(-b));
    }

    const size_t base = (size_t)bh * S_ * D_;
    const int schunk = S_ / NS2, ngroups = schunk / 32;

    for (int g = wave; g < ngroups; g += 4) {
        const int row0 = p * schunk + g * 32;

        float sq[2][2][8];
        #pragma unroll
        for (int st = 0; st < 2; ++st) {
            const float* qr = Qp + base + (size_t)(row0 + st * 16 + c16) * D_;
            #pragma unroll
            for (int kk = 0; kk < 2; ++kk) {
                f32x4 a = *(const f32x4*)(qr + kk * 32 + g4 * 8);
                f32x4 b = *(const f32x4*)(qr + kk * 32 + g4 * 8 + 4);
                #pragma unroll
                for (int j = 0; j < 4; ++j) {
                    sq[st][kk][j]     = elup1(a[j]);
                    sq[st][kk][4 + j] = elup1(b[j]);
                }
            }
        }

        float n0 = 0.f, n1 = 0.f;
        #pragma unroll
        for (int kk = 0; kk < 2; ++kk)
        #pragma unroll
        for (int j = 0; j < 8; ++j) {
            n0 += sq[0][kk][j] * mzv[kk][j];
            n1 += sq[1][kk][j] * mzv[kk][j];
        }
        n0 += __shfl_xor(n0, 16); n0 += __shfl_xor(n0, 32);
        n1 += __shfl_xor(n1, 16); n1 += __shfl_xor(n1, 32);
        const float rn0 = __builtin_amdgcn_rcpf(n0 + EPS_);
        const float rn1 = __builtin_amdgcn_rcpf(n1 + EPS_);

        bf16x8 sqf[2][2];
        #pragma unroll
        for (int st = 0; st < 2; ++st)
        #pragma unroll
        for (int kk = 0; kk < 2; ++kk) {
            bf16x8 f;
            #pragma unroll
            for (int j = 0; j < 8; ++j) f[j] = (short)f2bf(sq[st][kk][j]);
            sqf[st][kk] = f;
        }

        f32x4 acc[2][4];
        #pragma unroll
        for (int st = 0; st < 2; ++st)
        #pragma unroll
        for (int et = 0; et < 4; ++et) {
            f32x4 t = __builtin_amdgcn_mfma_f32_16x16x32_bf16(mf[et][0], sqf[st][0], fzero(), 0, 0, 0);
            acc[st][et] = __builtin_amdgcn_mfma_f32_16x16x32_bf16(mf[et][1], sqf[st][1], t, 0, 0, 0);
        }

        #pragma unroll
        for (int st = 0; st < 2; ++st) {
            const float rn = st ? rn1 : rn0;
            const size_t roff = base + (size_t)(row0 + st * 16 + c16) * D_;
            #pragma unroll
            for (int et = 0; et < 4; ++et) {
                f32x4 o4 = *(const f32x4*)(Op + roff + et * 16 + g4 * 4);
                f32x4 wv;
                #pragma unroll
                for (int r = 0; r < 4; ++r) {
                    float t = acc[st][et][r] * rn;
                    wv[r] = o4[r] + gate[et][r] * (t - o4[r]);
                }
                *(f32x4*)(Out + roff + et * 16 + g4 * 4) = wv;
            }
        }
    }
}

// ---------------------------------------------------------------------------
extern "C" void kernel_launch(void* const* d_in, const int* in_sizes, int n_in,
                              void* d_out, int out_size, void* d_ws, size_t ws_size,
                              hipStream_t stream)
{
    const float* Q  = (const float*)d_in[0];
    const float* K  = (const float*)d_in[1];
    const float* V  = (const float*)d_in[2];
    const float* O  = (const float*)d_in[3];
    const float* Bt = (const float*)d_in[4];
    const float* W0 = (const float*)d_in[5];
    const float* Z0 = (const float*)d_in[6];
    float* Out = (float*)d_out;

    // ws: [Mpart NS*64*4096 bf16][Zpart NS*64*64 f32][Zfin 64*64 f32][MfinT 64*4096 bf16]
    int NS = 32;
    auto need = [](int ns) -> size_t {
        return sizeof(unsigned short) * ((size_t)ns * BH_ * 4096 + (size_t)BH_ * 4096) +
               sizeof(float) * ((size_t)ns * BH_ * 64 + (size_t)BH_ * 64);
    };
    while (NS > 1 && need(NS) > ws_size) NS >>= 1;

    unsigned short* Mpart = (unsigned short*)d_ws;
    float* Zpart = (float*)(Mpart + (size_t)NS * BH_ * 4096);
    float* Zfin  = Zpart + (size_t)NS * BH_ * 64;
    unsigned short* MfinT = (unsigned short*)(Zfin + (size_t)BH_ * 64);

    hipLaunchKernelGGL(k1_states, dim3(BH_ * NS), dim3(256), 0, stream,
                       K, V, W0, Z0, Mpart, Zpart, NS);
    hipLaunchKernelGGL(k_reduce, dim3(BH_ * 4), dim3(256), 0, stream,
                       Mpart, Zpart, W0, Z0, MfinT, Zfin, NS);
    hipLaunchKernelGGL(k2_out, dim3(BH_ * 32), dim3(256), 0, stream,
                       Q, O, Bt, MfinT, Zfin, Out, 32);
}

// Round 8
// 141.150 us; speedup vs baseline: 1.3450x; 1.3450x over previous
//
#include <hip/hip_runtime.h>
#include <hip/hip_bf16.h>

// PraxisMemory: one-shot delta-rule memory. B=4,H=16,S=4096,D=64, all f32 I/O.
//
// Gram reformulation:  M = W0 + sigma_k^T @ V - (sigma_k^T diag(1/den) sigma_k) @ W0
//                        = W0 + MP1 - G @ W0
// k1 v8 (stage-once): per 128-row tile, wave w stages its 32-row group ONCE
//   (row-natural f32x4 loads, sigma+den once) into 3 shared transposed bf16
//   slabs (sigma^T, (sigma*rd)^T, V^T); barrier; each wave computes its
//   16-d strip over all 4 groups (9 MFMAs/group, b128 slab reads); barrier.
//   Register prefetch of next tile's K/V overlaps the MFMA phase.
// k_reduce: M = W0 + sum_p Mpart(bf16) -> MfinT bf16; z = z0 + sum Zpart.
// k2: proven (256,4) shape, grid BH*32, one 32-row group per wave.

#define B_  4
#define H_  16
#define S_  4096
#define D_  64
#define BH_ 64
#define EPS_ 1e-8f

typedef __attribute__((ext_vector_type(8))) short bf16x8;
typedef __attribute__((ext_vector_type(4))) float f32x4;
typedef __attribute__((ext_vector_type(4))) unsigned short u16x4;

__device__ __forceinline__ unsigned short f2bf(float x) {
    union { float f; unsigned u; } v; v.f = x;
    return (unsigned short)((v.u + 0x8000u) >> 16);   // round-half-up (cheap)
}
__device__ __forceinline__ float bf2f(unsigned short u) {
    union { unsigned u; float f; } v; v.u = ((unsigned)u) << 16;
    return v.f;
}
__device__ __forceinline__ float elup1(float x) {
    return x > 0.0f ? x + 1.0f : __expf(x);  // elu(x)+1
}
__device__ __forceinline__ f32x4 fzero() { f32x4 z = {0.f, 0.f, 0.f, 0.f}; return z; }
__device__ __forceinline__ unsigned pk2(float a, float b) {
    return (unsigned)f2bf(a) | ((unsigned)f2bf(b) << 16);
}

// ---------------------------------------------------------------------------
// Kernel 1. MFMA 16x16x32 bf16 conventions (verified across rounds):
//   A-frag: lane m = l&15, per-lane k = (l>>4)*8 + j
//   B-frag: lane n = l&15, same k bijection (consistent on both operands)
//   C/D:    lane l, reg r -> row m = (l>>4)*4 + r, col n = l&15
// Slabs: [group][d-row 64][s 32] bf16, pitch 40 u16 (80 B -> b128-aligned).
// Lane (c16,g4) stages rows sA=2*c16, sA+1 and cols kk*32+g4*8+j; packed-pair
// b32 writes land at u32 idx d*20 + c16. b128 reads: u32 idx d*20 + g4*4.
// ---------------------------------------------------------------------------
__global__ __launch_bounds__(256, 2) void k1_states(
    const float* __restrict__ Kp, const float* __restrict__ Vp,
    const float* __restrict__ W0, const float* __restrict__ Z0,
    unsigned short* __restrict__ Mpart, float* __restrict__ Zpart, int NS)
{
    const int bid = blockIdx.x;
    const int bh  = bid / NS;
    const int p   = bid % NS;
    const int h   = bh & (H_ - 1);
    const int tid  = threadIdx.x;
    const int lane = tid & 63;
    const int w    = tid >> 6;     // wave = staging group = d-strip owner
    const int c16  = lane & 15;
    const int g4   = lane >> 4;

    __shared__ unsigned skT[4][64 * 20];   // sigma^T (packed s-pairs)
    __shared__ unsigned sks[4][64 * 20];   // (sigma*rd)^T
    __shared__ unsigned vT [4][64 * 20];   // V^T                  (61440 B total)

    // z0 slice at cols kk*32+g4*8+j
    float z0l[2][8];
    #pragma unroll
    for (int kk = 0; kk < 2; ++kk) {
        f32x4 a = *(const f32x4*)(Z0 + h * 64 + kk * 32 + g4 * 8);
        f32x4 b = *(const f32x4*)(Z0 + h * 64 + kk * 32 + g4 * 8 + 4);
        #pragma unroll
        for (int j = 0; j < 4; ++j) { z0l[kk][j] = a[j]; z0l[kk][4 + j] = b[j]; }
    }

    bf16x8 ones;
    #pragma unroll
    for (int j = 0; j < 8; ++j) ones[j] = (short)0x3F80;  // bf16 1.0

    const size_t base   = (size_t)bh * S_ * D_;
    const int    schunk = S_ / NS;
    const int    ntiles = schunk >> 7;      // 128 rows per tile
    const int    sA     = 2 * c16;          // local row pair within group

    f32x4 mp1[4], gac[4], zac = fzero();
    #pragma unroll
    for (int i = 0; i < 4; ++i) { mp1[i] = fzero(); gac[i] = fzero(); }

    f32x4 kb[8], vb[8];
    auto LOAD = [&](int t, f32x4* k8, f32x4* v8) {
        const float* kr = Kp + base + (size_t)(p * schunk + t * 128 + w * 32 + sA) * 64;
        const float* vr = Vp + base + (size_t)(p * schunk + t * 128 + w * 32 + sA) * 64;
        #pragma unroll
        for (int row = 0; row < 2; ++row)
        #pragma unroll
        for (int kk = 0; kk < 2; ++kk) {
            k8[row * 4 + kk * 2 + 0] = *(const f32x4*)(kr + row * 64 + kk * 32 + g4 * 8);
            k8[row * 4 + kk * 2 + 1] = *(const f32x4*)(kr + row * 64 + kk * 32 + g4 * 8 + 4);
            v8[row * 4 + kk * 2 + 0] = *(const f32x4*)(vr + row * 64 + kk * 32 + g4 * 8);
            v8[row * 4 + kk * 2 + 1] = *(const f32x4*)(vr + row * 64 + kk * 32 + g4 * 8 + 4);
        }
    };

    LOAD(0, kb, vb);

    #pragma unroll 1
    for (int t = 0; t < ntiles; ++t) {
        // ---- stage own group: sigma + den once, transposed packed writes ----
        float s0v[2][8], s1v[2][8];
        float d0 = 0.f, d1 = 0.f;
        #pragma unroll
        for (int kk = 0; kk < 2; ++kk)
        #pragma unroll
        for (int half = 0; half < 2; ++half)
        #pragma unroll
        for (int q = 0; q < 4; ++q) {
            int j = half * 4 + q;
            float a0 = elup1(kb[0 + kk * 2 + half][q]);
            float a1 = elup1(kb[4 + kk * 2 + half][q]);
            s0v[kk][j] = a0; s1v[kk][j] = a1;
            d0 += a0 * z0l[kk][j];
            d1 += a1 * z0l[kk][j];
        }
        d0 += __shfl_xor(d0, 16); d0 += __shfl_xor(d0, 32);
        d1 += __shfl_xor(d1, 16); d1 += __shfl_xor(d1, 32);
        const float r0 = __builtin_amdgcn_rcpf(d0 + EPS_);
        const float r1 = __builtin_amdgcn_rcpf(d1 + EPS_);

        #pragma unroll
        for (int kk = 0; kk < 2; ++kk)
        #pragma unroll
        for (int j = 0; j < 8; ++j) {
            const int d = kk * 32 + g4 * 8 + j;
            const int o = d * 20 + c16;
            skT[w][o] = pk2(s0v[kk][j], s1v[kk][j]);
            sks[w][o] = pk2(s0v[kk][j] * r0, s1v[kk][j] * r1);
            vT [w][o] = pk2(vb[0 + kk * 2 + (j >> 2)][j & 3],
                            vb[4 + kk * 2 + (j >> 2)][j & 3]);
        }
        __syncthreads();

        // ---- prefetch next tile during MFMA phase ----
        f32x4 kb2[8], vb2[8];
        const bool more = (t + 1 < ntiles);
        if (more) LOAD(t + 1, kb2, vb2);

        // ---- MFMA: own d-strip over all 4 groups ----
        #pragma unroll
        for (int g = 0; g < 4; ++g) {
            bf16x8 A = *(const bf16x8*)&skT[g][(w * 16 + c16) * 20 + g4 * 4];
            zac = __builtin_amdgcn_mfma_f32_16x16x32_bf16(A, ones, zac, 0, 0, 0);
            #pragma unroll
            for (int q = 0; q < 4; ++q) {
                bf16x8 Bq = *(const bf16x8*)&sks[g][(q * 16 + c16) * 20 + g4 * 4];
                gac[q] = __builtin_amdgcn_mfma_f32_16x16x32_bf16(A, Bq, gac[q], 0, 0, 0);
            }
            #pragma unroll
            for (int nt = 0; nt < 4; ++nt) {
                bf16x8 Bv = *(const bf16x8*)&vT[g][(nt * 16 + c16) * 20 + g4 * 4];
                mp1[nt] = __builtin_amdgcn_mfma_f32_16x16x32_bf16(A, Bv, mp1[nt], 0, 0, 0);
            }
        }
        __syncthreads();

        if (more) {
            #pragma unroll
            for (int i = 0; i < 8; ++i) { kb[i] = kb2[i]; vb[i] = vb2[i]; }
        }
    }

    // ================= epilogue (wave-private in own slab regions) ==========
    // G strip -> Gl (reuse skT[w]): rows strip-local m, cols absolute d'
    float* Gl = (float*)&skT[w][0];            // [16][68]
    #pragma unroll
    for (int q = 0; q < 4; ++q)
    #pragma unroll
    for (int r = 0; r < 4; ++r)
        Gl[(g4 * 4 + r) * 68 + q * 16 + c16] = gac[q][r];

    bf16x8 ag[2];
    #pragma unroll
    for (int kk = 0; kk < 2; ++kk)
    #pragma unroll
    for (int j = 0; j < 8; ++j)
        ag[kk][j] = (short)f2bf(Gl[c16 * 68 + kk * 32 + g4 * 8 + j]);

    // GW0 via W0 B-frag gathers (L2-resident); rr = MP1 - G@W0
    f32x4 rr[4];
    #pragma unroll
    for (int nt = 0; nt < 4; ++nt) {
        bf16x8 wb0, wb1;
        #pragma unroll
        for (int j = 0; j < 8; ++j) {
            wb0[j] = (short)f2bf(W0[(size_t)h * 4096 + (g4 * 8 + j) * 64 + nt * 16 + c16]);
            wb1[j] = (short)f2bf(W0[(size_t)h * 4096 + (32 + g4 * 8 + j) * 64 + nt * 16 + c16]);
        }
        f32x4 tt = __builtin_amdgcn_mfma_f32_16x16x32_bf16(ag[0], wb0, fzero(), 0, 0, 0);
        tt = __builtin_amdgcn_mfma_f32_16x16x32_bf16(ag[1], wb1, tt, 0, 0, 0);
        rr[nt] = mp1[nt] - tt;
    }

    // stage rr in sks[w] region, then coalesced bf16 stores
    float* Rl = (float*)&sks[w][0];            // [16][68]
    #pragma unroll
    for (int nt = 0; nt < 4; ++nt)
    #pragma unroll
    for (int r = 0; r < 4; ++r)
        Rl[(g4 * 4 + r) * 68 + nt * 16 + c16] = rr[nt][r];

    unsigned short* mout = Mpart + ((size_t)p * BH_ + bh) * 4096 + w * 1024;
    #pragma unroll
    for (int i = 0; i < 4; ++i) {
        int o = i * 256 + lane * 4;
        int dl = o >> 6, e = o & 63;
        u16x4 pk;
        #pragma unroll
        for (int j = 0; j < 4; ++j) pk[j] = f2bf(Rl[dl * 68 + e + j]);
        *(u16x4*)(mout + o) = pk;
    }

    if (c16 == 0) {
        #pragma unroll
        for (int r = 0; r < 4; ++r)
            Zpart[((size_t)p * BH_ + bh) * 64 + w * 16 + g4 * 4 + r] = zac[r];
    }
}

// ---------------------------------------------------------------------------
// Reduce: M = W0 + sum_p Mpart(bf16) -> MfinT bf16 [bh][e*64+d];
// z = z0 + sum Zpart. Grid = BH_*4; block handles d-rows [q*16, q*16+16).
// ---------------------------------------------------------------------------
__global__ void k_reduce(const unsigned short* __restrict__ Mpart, const float* __restrict__ Zpart,
                         const float* __restrict__ W0, const float* __restrict__ Z0,
                         unsigned short* __restrict__ MfinT, float* __restrict__ Zfin, int NS)
{
    const int bh = blockIdx.x >> 2, q = blockIdx.x & 3;
    const int h = bh & (H_ - 1), t = threadIdx.x;
    __shared__ float Ml[16][65];

    const int o = q * 1024 + t * 4;          // linear d*64+e
    f32x4 s = *(const f32x4*)(W0 + (size_t)h * 4096 + o);
    for (int p = 0; p < NS; ++p) {
        u16x4 v = *(const u16x4*)(Mpart + ((size_t)p * BH_ + bh) * 4096 + o);
        #pragma unroll
        for (int j = 0; j < 4; ++j) s[j] += bf2f(v[j]);
    }
    const int dl = t >> 4, e0 = (t & 15) * 4;
    #pragma unroll
    for (int j = 0; j < 4; ++j) Ml[dl][e0 + j] = s[j];
    __syncthreads();

    const int e = t >> 2, dd0 = (t & 3) * 4;
    u16x4 wv;
    #pragma unroll
    for (int j = 0; j < 4; ++j) wv[j] = f2bf(Ml[dd0 + j][e]);
    *(u16x4*)(MfinT + (size_t)bh * 4096 + e * 64 + q * 16 + dd0) = wv;

    if (q == 0 && t < 64) {
        float zs = Z0[h * 64 + t];
        for (int p = 0; p < NS; ++p) zs += Zpart[((size_t)p * BH_ + bh) * 64 + t];
        Zfin[bh * 64 + t] = zs;
    }
}

// ---------------------------------------------------------------------------
// Kernel 2 (proven): 256-thr, (256,4), grid BH_*NS2; wave handles one 32-row
// group. RET^T = M^T @ SQ^T ; out = O + gate*(RET/norm - O). No LDS.
// ---------------------------------------------------------------------------
__global__ __launch_bounds__(256, 4) void k2_out(
    const float* __restrict__ Qp, const float* __restrict__ Op,
    const float* __restrict__ Bp, const unsigned short* __restrict__ MfinT,
    const float* __restrict__ Zfin, float* __restrict__ Out, int NS2)
{
    const int bh = blockIdx.x / NS2;
    const int p  = blockIdx.x % NS2;
    const int h  = bh & (H_ - 1);
    const int tid = threadIdx.x, lane = tid & 63, wave = tid >> 6;
    const int c16 = lane & 15, g4 = lane >> 4;

    float mzv[2][8];
    #pragma unroll
    for (int kk = 0; kk < 2; ++kk) {
        f32x4 a = *(const f32x4*)(Zfin + bh * 64 + kk * 32 + g4 * 8);
        f32x4 b = *(const f32x4*)(Zfin + bh * 64 + kk * 32 + g4 * 8 + 4);
        #pragma unroll
        for (int j = 0; j < 4; ++j) { mzv[kk][j] = a[j]; mzv[kk][4 + j] = b[j]; }
    }

    bf16x8 mf[4][2];  // M^T A-frags, straight b128 loads
    #pragma unroll
    for (int et = 0; et < 4; ++et)
    #pragma unroll
    for (int kk = 0; kk < 2; ++kk)
        mf[et][kk] = *(const bf16x8*)(MfinT + (size_t)bh * 4096 + (et * 16 + c16) * 64 + kk * 32 + g4 * 8);

    float gate[4][4];
    #pragma unroll
    for (int et = 0; et < 4; ++et)
    #pragma unroll
    for (int r = 0; r < 4; ++r) {
        float b = Bp[h * 64 + et * 16 + g4 * 4 + r];
        gate[et][r] = 1.0f / (1.0f + __expf(-b));
    }

    const size_t base = (size_t)bh * S_ * D_;
    const int schunk = S_ / NS2, ngroups = schunk / 32;

    for (int g = wave; g < ngroups; g += 4) {
        const int row0 = p * schunk + g * 32;

        float sq[2][2][8];
        #pragma unroll
        for (int st = 0; st < 2; ++st) {
            const float* qr = Qp + base + (size_t)(row0 + st * 16 + c16) * D_;
            #pragma unroll
            for (int kk = 0; kk < 2; ++kk) {
                f32x4 a = *(const f32x4*)(qr + kk * 32 + g4 * 8);
                f32x4 b = *(const f32x4*)(qr + kk * 32 + g4 * 8 + 4);
                #pragma unroll
                for (int j = 0; j < 4; ++j) {
                    sq[st][kk][j]     = elup1(a[j]);
                    sq[st][kk][4 + j] = elup1(b[j]);
                }
            }
        }

        float n0 = 0.f, n1 = 0.f;
        #pragma unroll
        for (int kk = 0; kk < 2; ++kk)
        #pragma unroll
        for (int j = 0; j < 8; ++j) {
            n0 += sq[0][kk][j] * mzv[kk][j];
            n1 += sq[1][kk][j] * mzv[kk][j];
        }
        n0 += __shfl_xor(n0, 16); n0 += __shfl_xor(n0, 32);
        n1 += __shfl_xor(n1, 16); n1 += __shfl_xor(n1, 32);
        const float rn0 = __builtin_amdgcn_rcpf(n0 + EPS_);
        const float rn1 = __builtin_amdgcn_rcpf(n1 + EPS_);

        bf16x8 sqf[2][2];
        #pragma unroll
        for (int st = 0; st < 2; ++st)
        #pragma unroll
        for (int kk = 0; kk < 2; ++kk) {
            bf16x8 f;
            #pragma unroll
            for (int j = 0; j < 8; ++j) f[j] = (short)f2bf(sq[st][kk][j]);
            sqf[st][kk] = f;
        }

        f32x4 acc[2][4];
        #pragma unroll
        for (int st = 0; st < 2; ++st)
        #pragma unroll
        for (int et = 0; et < 4; ++et) {
            f32x4 t = __builtin_amdgcn_mfma_f32_16x16x32_bf16(mf[et][0], sqf[st][0], fzero(), 0, 0, 0);
            acc[st][et] = __builtin_amdgcn_mfma_f32_16x16x32_bf16(mf[et][1], sqf[st][1], t, 0, 0, 0);
        }

        #pragma unroll
        for (int st = 0; st < 2; ++st) {
            const float rn = st ? rn1 : rn0;
            const size_t roff = base + (size_t)(row0 + st * 16 + c16) * D_;
            #pragma unroll
            for (int et = 0; et < 4; ++et) {
                f32x4 o4 = *(const f32x4*)(Op + roff + et * 16 + g4 * 4);
                f32x4 wv;
                #pragma unroll
                for (int r = 0; r < 4; ++r) {
                    float t = acc[st][et][r] * rn;
                    wv[r] = o4[r] + gate[et][r] * (t - o4[r]);
                }
                *(f32x4*)(Out + roff + et * 16 + g4 * 4) = wv;
            }
        }
    }
}

// ---------------------------------------------------------------------------
extern "C" void kernel_launch(void* const* d_in, const int* in_sizes, int n_in,
                              void* d_out, int out_size, void* d_ws, size_t ws_size,
                              hipStream_t stream)
{
    const float* Q  = (const float*)d_in[0];
    const float* K  = (const float*)d_in[1];
    const float* V  = (const float*)d_in[2];
    const float* O  = (const float*)d_in[3];
    const float* Bt = (const float*)d_in[4];
    const float* W0 = (const float*)d_in[5];
    const float* Z0 = (const float*)d_in[6];
    float* Out = (float*)d_out;

    // ws: [Mpart NS*64*4096 bf16][Zpart NS*64*64 f32][Zfin 64*64 f32][MfinT 64*4096 bf16]
    int NS = 16;
    auto need = [](int ns) -> size_t {
        return sizeof(unsigned short) * ((size_t)ns * BH_ * 4096 + (size_t)BH_ * 4096) +
               sizeof(float) * ((size_t)ns * BH_ * 64 + (size_t)BH_ * 64);
    };
    while (NS > 1 && need(NS) > ws_size) NS >>= 1;

    unsigned short* Mpart = (unsigned short*)d_ws;
    float* Zpart = (float*)(Mpart + (size_t)NS * BH_ * 4096);
    float* Zfin  = Zpart + (size_t)NS * BH_ * 64;
    unsigned short* MfinT = (unsigned short*)(Zfin + (size_t)BH_ * 64);

    hipLaunchKernelGGL(k1_states, dim3(BH_ * NS), dim3(256), 0, stream,
                       K, V, W0, Z0, Mpart, Zpart, NS);
    hipLaunchKernelGGL(k_reduce, dim3(BH_ * 4), dim3(256), 0, stream,
                       Mpart, Zpart, W0, Z0, MfinT, Zfin, NS);
    hipLaunchKernelGGL(k2_out, dim3(BH_ * 32), dim3(256), 0, stream,
                       Q, O, Bt, MfinT, Zfin, Out, 32);
}

// Round 9
// 97.022 us; speedup vs baseline: 1.9568x; 1.4548x over previous
//
#include <hip/hip_runtime.h>
#include <hip/hip_bf16.h>

// PraxisMemory: one-shot delta-rule memory. B=4,H=16,S=4096,D=64, all f32 I/O.
//
// Gram reformulation:  M = W0 + sigma_k^T @ V - (sigma_k^T diag(1/den) sigma_k) @ W0
//                        = W0 + MP1 - G @ W0
// k1 v8 (unchanged from R8): stage-once shared transposed bf16 slabs.
// k_reduce (unchanged): M = W0 + sum_p Mpart(bf16) -> MfinT bf16; z reduce.
// k2 v9: low-register restructure at (256,4) — norm via mz-broadcast MFMA
//   (kills dot+shfl+mzv), phase-ordered live ranges (Q->sigma->MFMA->epilogue),
//   gate/O loads only after mf frags are dead. No spill (R8: 138 MB scratch).

#define B_  4
#define H_  16
#define S_  4096
#define D_  64
#define BH_ 64
#define EPS_ 1e-8f

typedef __attribute__((ext_vector_type(8))) short bf16x8;
typedef __attribute__((ext_vector_type(4))) float f32x4;
typedef __attribute__((ext_vector_type(4))) unsigned short u16x4;

__device__ __forceinline__ unsigned short f2bf(float x) {
    union { float f; unsigned u; } v; v.f = x;
    return (unsigned short)((v.u + 0x8000u) >> 16);   // round-half-up (cheap)
}
__device__ __forceinline__ float bf2f(unsigned short u) {
    union { unsigned u; float f; } v; v.u = ((unsigned)u) << 16;
    return v.f;
}
__device__ __forceinline__ float elup1(float x) {
    return x > 0.0f ? x + 1.0f : __expf(x);  // elu(x)+1
}
__device__ __forceinline__ f32x4 fzero() { f32x4 z = {0.f, 0.f, 0.f, 0.f}; return z; }
__device__ __forceinline__ unsigned pk2(float a, float b) {
    return (unsigned)f2bf(a) | ((unsigned)f2bf(b) << 16);
}

// ---------------------------------------------------------------------------
// Kernel 1 (unchanged). MFMA 16x16x32 bf16 conventions (verified):
//   A-frag: lane m = l&15, per-lane k = (l>>4)*8 + j
//   B-frag: lane n = l&15, same k bijection
//   C/D:    lane l, reg r -> row m = (l>>4)*4 + r, col n = l&15
// ---------------------------------------------------------------------------
__global__ __launch_bounds__(256, 2) void k1_states(
    const float* __restrict__ Kp, const float* __restrict__ Vp,
    const float* __restrict__ W0, const float* __restrict__ Z0,
    unsigned short* __restrict__ Mpart, float* __restrict__ Zpart, int NS)
{
    const int bid = blockIdx.x;
    const int bh  = bid / NS;
    const int p   = bid % NS;
    const int h   = bh & (H_ - 1);
    const int tid  = threadIdx.x;
    const int lane = tid & 63;
    const int w    = tid >> 6;     // wave = staging group = d-strip owner
    const int c16  = lane & 15;
    const int g4   = lane >> 4;

    __shared__ unsigned skT[4][64 * 20];   // sigma^T (packed s-pairs)
    __shared__ unsigned sks[4][64 * 20];   // (sigma*rd)^T
    __shared__ unsigned vT [4][64 * 20];   // V^T                  (61440 B total)

    float z0l[2][8];
    #pragma unroll
    for (int kk = 0; kk < 2; ++kk) {
        f32x4 a = *(const f32x4*)(Z0 + h * 64 + kk * 32 + g4 * 8);
        f32x4 b = *(const f32x4*)(Z0 + h * 64 + kk * 32 + g4 * 8 + 4);
        #pragma unroll
        for (int j = 0; j < 4; ++j) { z0l[kk][j] = a[j]; z0l[kk][4 + j] = b[j]; }
    }

    bf16x8 ones;
    #pragma unroll
    for (int j = 0; j < 8; ++j) ones[j] = (short)0x3F80;  // bf16 1.0

    const size_t base   = (size_t)bh * S_ * D_;
    const int    schunk = S_ / NS;
    const int    ntiles = schunk >> 7;      // 128 rows per tile
    const int    sA     = 2 * c16;          // local row pair within group

    f32x4 mp1[4], gac[4], zac = fzero();
    #pragma unroll
    for (int i = 0; i < 4; ++i) { mp1[i] = fzero(); gac[i] = fzero(); }

    f32x4 kb[8], vb[8];
    auto LOAD = [&](int t, f32x4* k8, f32x4* v8) {
        const float* kr = Kp + base + (size_t)(p * schunk + t * 128 + w * 32 + sA) * 64;
        const float* vr = Vp + base + (size_t)(p * schunk + t * 128 + w * 32 + sA) * 64;
        #pragma unroll
        for (int row = 0; row < 2; ++row)
        #pragma unroll
        for (int kk = 0; kk < 2; ++kk) {
            k8[row * 4 + kk * 2 + 0] = *(const f32x4*)(kr + row * 64 + kk * 32 + g4 * 8);
            k8[row * 4 + kk * 2 + 1] = *(const f32x4*)(kr + row * 64 + kk * 32 + g4 * 8 + 4);
            v8[row * 4 + kk * 2 + 0] = *(const f32x4*)(vr + row * 64 + kk * 32 + g4 * 8);
            v8[row * 4 + kk * 2 + 1] = *(const f32x4*)(vr + row * 64 + kk * 32 + g4 * 8 + 4);
        }
    };

    LOAD(0, kb, vb);

    #pragma unroll 1
    for (int t = 0; t < ntiles; ++t) {
        float s0v[2][8], s1v[2][8];
        float d0 = 0.f, d1 = 0.f;
        #pragma unroll
        for (int kk = 0; kk < 2; ++kk)
        #pragma unroll
        for (int half = 0; half < 2; ++half)
        #pragma unroll
        for (int q = 0; q < 4; ++q) {
            int j = half * 4 + q;
            float a0 = elup1(kb[0 + kk * 2 + half][q]);
            float a1 = elup1(kb[4 + kk * 2 + half][q]);
            s0v[kk][j] = a0; s1v[kk][j] = a1;
            d0 += a0 * z0l[kk][j];
            d1 += a1 * z0l[kk][j];
        }
        d0 += __shfl_xor(d0, 16); d0 += __shfl_xor(d0, 32);
        d1 += __shfl_xor(d1, 16); d1 += __shfl_xor(d1, 32);
        const float r0 = __builtin_amdgcn_rcpf(d0 + EPS_);
        const float r1 = __builtin_amdgcn_rcpf(d1 + EPS_);

        #pragma unroll
        for (int kk = 0; kk < 2; ++kk)
        #pragma unroll
        for (int j = 0; j < 8; ++j) {
            const int d = kk * 32 + g4 * 8 + j;
            const int o = d * 20 + c16;
            skT[w][o] = pk2(s0v[kk][j], s1v[kk][j]);
            sks[w][o] = pk2(s0v[kk][j] * r0, s1v[kk][j] * r1);
            vT [w][o] = pk2(vb[0 + kk * 2 + (j >> 2)][j & 3],
                            vb[4 + kk * 2 + (j >> 2)][j & 3]);
        }
        __syncthreads();

        f32x4 kb2[8], vb2[8];
        const bool more = (t + 1 < ntiles);
        if (more) LOAD(t + 1, kb2, vb2);

        #pragma unroll
        for (int g = 0; g < 4; ++g) {
            bf16x8 A = *(const bf16x8*)&skT[g][(w * 16 + c16) * 20 + g4 * 4];
            zac = __builtin_amdgcn_mfma_f32_16x16x32_bf16(A, ones, zac, 0, 0, 0);
            #pragma unroll
            for (int q = 0; q < 4; ++q) {
                bf16x8 Bq = *(const bf16x8*)&sks[g][(q * 16 + c16) * 20 + g4 * 4];
                gac[q] = __builtin_amdgcn_mfma_f32_16x16x32_bf16(A, Bq, gac[q], 0, 0, 0);
            }
            #pragma unroll
            for (int nt = 0; nt < 4; ++nt) {
                bf16x8 Bv = *(const bf16x8*)&vT[g][(nt * 16 + c16) * 20 + g4 * 4];
                mp1[nt] = __builtin_amdgcn_mfma_f32_16x16x32_bf16(A, Bv, mp1[nt], 0, 0, 0);
            }
        }
        __syncthreads();

        if (more) {
            #pragma unroll
            for (int i = 0; i < 8; ++i) { kb[i] = kb2[i]; vb[i] = vb2[i]; }
        }
    }

    // epilogue (wave-private in own slab regions)
    float* Gl = (float*)&skT[w][0];            // [16][68]
    #pragma unroll
    for (int q = 0; q < 4; ++q)
    #pragma unroll
    for (int r = 0; r < 4; ++r)
        Gl[(g4 * 4 + r) * 68 + q * 16 + c16] = gac[q][r];

    bf16x8 ag[2];
    #pragma unroll
    for (int kk = 0; kk < 2; ++kk)
    #pragma unroll
    for (int j = 0; j < 8; ++j)
        ag[kk][j] = (short)f2bf(Gl[c16 * 68 + kk * 32 + g4 * 8 + j]);

    f32x4 rr[4];
    #pragma unroll
    for (int nt = 0; nt < 4; ++nt) {
        bf16x8 wb0, wb1;
        #pragma unroll
        for (int j = 0; j < 8; ++j) {
            wb0[j] = (short)f2bf(W0[(size_t)h * 4096 + (g4 * 8 + j) * 64 + nt * 16 + c16]);
            wb1[j] = (short)f2bf(W0[(size_t)h * 4096 + (32 + g4 * 8 + j) * 64 + nt * 16 + c16]);
        }
        f32x4 tt = __builtin_amdgcn_mfma_f32_16x16x32_bf16(ag[0], wb0, fzero(), 0, 0, 0);
        tt = __builtin_amdgcn_mfma_f32_16x16x32_bf16(ag[1], wb1, tt, 0, 0, 0);
        rr[nt] = mp1[nt] - tt;
    }

    float* Rl = (float*)&sks[w][0];            // [16][68]
    #pragma unroll
    for (int nt = 0; nt < 4; ++nt)
    #pragma unroll
    for (int r = 0; r < 4; ++r)
        Rl[(g4 * 4 + r) * 68 + nt * 16 + c16] = rr[nt][r];

    unsigned short* mout = Mpart + ((size_t)p * BH_ + bh) * 4096 + w * 1024;
    #pragma unroll
    for (int i = 0; i < 4; ++i) {
        int o = i * 256 + lane * 4;
        int dl = o >> 6, e = o & 63;
        u16x4 pk;
        #pragma unroll
        for (int j = 0; j < 4; ++j) pk[j] = f2bf(Rl[dl * 68 + e + j]);
        *(u16x4*)(mout + o) = pk;
    }

    if (c16 == 0) {
        #pragma unroll
        for (int r = 0; r < 4; ++r)
            Zpart[((size_t)p * BH_ + bh) * 64 + w * 16 + g4 * 4 + r] = zac[r];
    }
}

// ---------------------------------------------------------------------------
// Reduce (unchanged): M = W0 + sum_p Mpart(bf16) -> MfinT bf16 [bh][e*64+d];
// z = z0 + sum Zpart. Grid = BH_*4; block handles d-rows [q*16, q*16+16).
// ---------------------------------------------------------------------------
__global__ void k_reduce(const unsigned short* __restrict__ Mpart, const float* __restrict__ Zpart,
                         const float* __restrict__ W0, const float* __restrict__ Z0,
                         unsigned short* __restrict__ MfinT, float* __restrict__ Zfin, int NS)
{
    const int bh = blockIdx.x >> 2, q = blockIdx.x & 3;
    const int h = bh & (H_ - 1), t = threadIdx.x;
    __shared__ float Ml[16][65];

    const int o = q * 1024 + t * 4;          // linear d*64+e
    f32x4 s = *(const f32x4*)(W0 + (size_t)h * 4096 + o);
    for (int p = 0; p < NS; ++p) {
        u16x4 v = *(const u16x4*)(Mpart + ((size_t)p * BH_ + bh) * 4096 + o);
        #pragma unroll
        for (int j = 0; j < 4; ++j) s[j] += bf2f(v[j]);
    }
    const int dl = t >> 4, e0 = (t & 15) * 4;
    #pragma unroll
    for (int j = 0; j < 4; ++j) Ml[dl][e0 + j] = s[j];
    __syncthreads();

    const int e = t >> 2, dd0 = (t & 3) * 4;
    u16x4 wv;
    #pragma unroll
    for (int j = 0; j < 4; ++j) wv[j] = f2bf(Ml[dd0 + j][e]);
    *(u16x4*)(MfinT + (size_t)bh * 4096 + e * 64 + q * 16 + dd0) = wv;

    if (q == 0 && t < 64) {
        float zs = Z0[h * 64 + t];
        for (int p = 0; p < NS; ++p) zs += Zpart[((size_t)p * BH_ + bh) * 64 + t];
        Zfin[bh * 64 + t] = zs;
    }
}

// ---------------------------------------------------------------------------
// Kernel 2 v9: low-pressure restructure. 256-thr, (256,4), grid BH_*NS2;
// wave handles one 32-row group.
//   norm[s] = sigma_q[s].mz computed by an extra MFMA with broadcast A-frag
//   (A[m][k] = mz[k] for all m) -> D[m][n=s] = norm[s]; lane c16 holds its
//   own row's norm in every reg (no shuffle, no f32 mzv array).
//   Phases: Q loads -> sigma/cvt (per st, frees Q regs) -> 10 MFMAs ->
//   epilogue (Bp gate + O loads only after mf frags dead). Peak regs ~124.
// ---------------------------------------------------------------------------
__global__ __launch_bounds__(256, 4) void k2_out(
    const float* __restrict__ Qp, const float* __restrict__ Op,
    const float* __restrict__ Bp, const unsigned short* __restrict__ MfinT,
    const float* __restrict__ Zfin, float* __restrict__ Out, int NS2)
{
    const int bh = blockIdx.x / NS2;
    const int p  = blockIdx.x % NS2;
    const int h  = bh & (H_ - 1);
    const int tid = threadIdx.x, lane = tid & 63, wave = tid >> 6;
    const int c16 = lane & 15, g4 = lane >> 4;

    // mz broadcast A-frag: amz[kk][j] = bf16(mz[kk*32+g4*8+j]) (same all c16)
    bf16x8 amz[2];
    #pragma unroll
    for (int kk = 0; kk < 2; ++kk) {
        f32x4 a = *(const f32x4*)(Zfin + bh * 64 + kk * 32 + g4 * 8);
        f32x4 b = *(const f32x4*)(Zfin + bh * 64 + kk * 32 + g4 * 8 + 4);
        #pragma unroll
        for (int j = 0; j < 4; ++j) {
            amz[kk][j]     = (short)f2bf(a[j]);
            amz[kk][4 + j] = (short)f2bf(b[j]);
        }
    }

    bf16x8 mf[4][2];  // M^T A-frags, straight b128 loads
    #pragma unroll
    for (int et = 0; et < 4; ++et)
    #pragma unroll
    for (int kk = 0; kk < 2; ++kk)
        mf[et][kk] = *(const bf16x8*)(MfinT + (size_t)bh * 4096 + (et * 16 + c16) * 64 + kk * 32 + g4 * 8);

    const size_t base = (size_t)bh * S_ * D_;
    const int schunk = S_ / NS2, ngroups = schunk / 32;

    #pragma unroll 1
    for (int g = wave; g < ngroups; g += 4) {
        const int row0 = p * schunk + g * 32;

        // ---- phase 1: Q loads (8 x f32x4 in flight) ----
        f32x4 qa[2][4];
        #pragma unroll
        for (int st = 0; st < 2; ++st) {
            const float* qr = Qp + base + (size_t)(row0 + st * 16 + c16) * D_;
            #pragma unroll
            for (int kk = 0; kk < 2; ++kk) {
                qa[st][kk * 2 + 0] = *(const f32x4*)(qr + kk * 32 + g4 * 8);
                qa[st][kk * 2 + 1] = *(const f32x4*)(qr + kk * 32 + g4 * 8 + 4);
            }
        }

        // ---- phase 2: sigma + convert (qa freed per st) ----
        bf16x8 sqf[2][2];
        #pragma unroll
        for (int st = 0; st < 2; ++st)
        #pragma unroll
        for (int kk = 0; kk < 2; ++kk)
        #pragma unroll
        for (int j = 0; j < 8; ++j)
            sqf[st][kk][j] = (short)f2bf(elup1(qa[st][kk * 2 + (j >> 2)][j & 3]));

        // ---- phase 3: MFMAs (2 norm + 8 RET) ----
        f32x4 accn[2], acc[2][4];
        #pragma unroll
        for (int st = 0; st < 2; ++st) {
            f32x4 t = __builtin_amdgcn_mfma_f32_16x16x32_bf16(amz[0], sqf[st][0], fzero(), 0, 0, 0);
            accn[st] = __builtin_amdgcn_mfma_f32_16x16x32_bf16(amz[1], sqf[st][1], t, 0, 0, 0);
            #pragma unroll
            for (int et = 0; et < 4; ++et) {
                f32x4 u = __builtin_amdgcn_mfma_f32_16x16x32_bf16(mf[et][0], sqf[st][0], fzero(), 0, 0, 0);
                acc[st][et] = __builtin_amdgcn_mfma_f32_16x16x32_bf16(mf[et][1], sqf[st][1], u, 0, 0, 0);
            }
        }

        // ---- phase 4: epilogue (mf pressure gone) ----
        f32x4 gt[4];
        #pragma unroll
        for (int et = 0; et < 4; ++et) {
            f32x4 bp = *(const f32x4*)(Bp + h * 64 + et * 16 + g4 * 4);
            #pragma unroll
            for (int r = 0; r < 4; ++r) gt[et][r] = 1.0f / (1.0f + __expf(-bp[r]));
        }

        #pragma unroll
        for (int st = 0; st < 2; ++st) {
            const float rn = __builtin_amdgcn_rcpf(accn[st][0] + EPS_);
            const size_t roff = base + (size_t)(row0 + st * 16 + c16) * D_;
            f32x4 o4[4];
            #pragma unroll
            for (int et = 0; et < 4; ++et)
                o4[et] = *(const f32x4*)(Op + roff + et * 16 + g4 * 4);
            #pragma unroll
            for (int et = 0; et < 4; ++et) {
                f32x4 wv;
                #pragma unroll
                for (int r = 0; r < 4; ++r) {
                    float t = acc[st][et][r] * rn;
                    wv[r] = o4[et][r] + gt[et][r] * (t - o4[et][r]);
                }
                *(f32x4*)(Out + roff + et * 16 + g4 * 4) = wv;
            }
        }
    }
}

// ---------------------------------------------------------------------------
extern "C" void kernel_launch(void* const* d_in, const int* in_sizes, int n_in,
                              void* d_out, int out_size, void* d_ws, size_t ws_size,
                              hipStream_t stream)
{
    const float* Q  = (const float*)d_in[0];
    const float* K  = (const float*)d_in[1];
    const float* V  = (const float*)d_in[2];
    const float* O  = (const float*)d_in[3];
    const float* Bt = (const float*)d_in[4];
    const float* W0 = (const float*)d_in[5];
    const float* Z0 = (const float*)d_in[6];
    float* Out = (float*)d_out;

    // ws: [Mpart NS*64*4096 bf16][Zpart NS*64*64 f32][Zfin 64*64 f32][MfinT 64*4096 bf16]
    int NS = 16;
    auto need = [](int ns) -> size_t {
        return sizeof(unsigned short) * ((size_t)ns * BH_ * 4096 + (size_t)BH_ * 4096) +
               sizeof(float) * ((size_t)ns * BH_ * 64 + (size_t)BH_ * 64);
    };
    while (NS > 1 && need(NS) > ws_size) NS >>= 1;

    unsigned short* Mpart = (unsigned short*)d_ws;
    float* Zpart = (float*)(Mpart + (size_t)NS * BH_ * 4096);
    float* Zfin  = Zpart + (size_t)NS * BH_ * 64;
    unsigned short* MfinT = (unsigned short*)(Zfin + (size_t)BH_ * 64);

    hipLaunchKernelGGL(k1_states, dim3(BH_ * NS), dim3(256), 0, stream,
                       K, V, W0, Z0, Mpart, Zpart, NS);
    hipLaunchKernelGGL(k_reduce, dim3(BH_ * 4), dim3(256), 0, stream,
                       Mpart, Zpart, W0, Z0, MfinT, Zfin, NS);
    hipLaunchKernelGGL(k2_out, dim3(BH_ * 32), dim3(256), 0, stream,
                       Q, O, Bt, MfinT, Zfin, Out, 32);
}